// Round 13
// baseline (557.800 us; speedup 1.0000x reference)
//
#include <hip/hip_runtime.h>
#include <hip/hip_bf16.h>

// GRU policy: B=2048, T=512, V=4, E=64, H=128.
// R12: TWO independent 16-row recurrences per block (32 rows, 1024 thr,
// 16 waves -> 2 waves of EACH group per SIMD). Block-wide __syncthreads is
// replaced by per-group LDS spin barriers (counter, acq/rel atomics,
// workgroup scope). The groups drift into antiphase, so group A's gate-VALU
// phase runs under group B's MFMA drain (m114 cross-wave co-scheduling) —
// the overlap that barrier-lockstep provably blocks (R4/R7/R10/R11 ledger).
// 64 blocks. Math identical to R9 (fused gate algebra, 12 MFMA/wave-step).

#define B_  2048
#define T_  512
#define V_  4
#define E_  64
#define H_  128
#define G3  384
#define SH  136            // h row stride (bf16 elems)

#define LOG2E 1.4426950408889634f

typedef __attribute__((ext_vector_type(8))) short  short8;   // 8 bf16
typedef __attribute__((ext_vector_type(4))) float  float4v;
typedef unsigned long long ull;

__device__ __forceinline__ short bf16s(float f) {            // RNE scalar (setup only)
  union { float ff; unsigned int u; } c; c.ff = f;
  return (short)((c.u + 0x7fffu + ((c.u >> 16) & 1u)) >> 16);
}

// table[v][g] = scale_g * (b_ih[g] + sum_e W_ih[g,e]*emb[v,e] (+ b_hh[g] for g<2H))
// scale_g = -log2e for r,z rows; +2*log2e for n rows (b_hh_n NOT folded).
__global__ void gi_table_kernel(const float* __restrict__ emb,
                                const float* __restrict__ W_ih,
                                const float* __restrict__ b_ih,
                                const float* __restrict__ b_hh,
                                float* __restrict__ table) {
  int gid = blockIdx.x * blockDim.x + threadIdx.x;
  if (gid >= V_ * G3) return;
  int v = gid / G3;
  int g = gid - v * G3;
  float acc = b_ih[g];
  if (g < 2 * H_) acc += b_hh[g];
  const float* wr = W_ih + g * E_;
  const float* er = emb + v * E_;
#pragma unroll 8
  for (int e = 0; e < E_; ++e) acc += wr[e] * er[e];
  table[gid] = acc * ((g < 2 * H_) ? -LOG2E : 2.f * LOG2E);
}

#define MFMA16(A, B, C) __builtin_amdgcn_mfma_f32_16x16x32_bf16((A), (B), (C), 0, 0, 0)

__global__ __launch_bounds__(1024, 1) void gru_kernel(
    const int* __restrict__ x, const float* __restrict__ W_hh,
    const float* __restrict__ b_hh, const float* __restrict__ W_fc,
    const float* __restrict__ b_fc, const float* __restrict__ table,
    float* __restrict__ out) {
  __shared__ __align__(16) short hbuf[2][2][16 * SH];          // [grp][buf] bf16 h
  __shared__ __align__(16) unsigned char xs[2][(T_ + 2) * 16]; // [grp] tokens + pad
  __shared__ __align__(16) float tabS[V_ * G3];                // gi table (shared)
  __shared__ __align__(16) float hf[2][16 * H_];               // [grp] epilogue h
  __shared__ int gctr[2];                                      // group barrier ctrs

  const int tid  = threadIdx.x;
  const int grp  = tid >> 9;        // 0 or 1 — independent recurrence group
  const int tid9 = tid & 511;       // index within group
  const int w    = tid9 >> 6;       // wave-in-group 0..7
  const int lane = tid & 63;
  const int m    = lane & 15;       // batch row (B/C col) and A gate-row
  const int q    = lane >> 4;       // quad
  const int g0   = blockIdx.x * 32 + grp * 16;

  // ---- stage x -> xs[grp][t][r]; zero pads; zero h; stage table; zero ctrs ----
  for (int i = tid; i < 32 * T_; i += 1024) {
    int rr = i >> 9;                // 0..31
    int t  = i & (T_ - 1);
    xs[rr >> 4][t * 16 + (rr & 15)] =
        (unsigned char)(x[(blockIdx.x * 32 + rr) * T_ + t] & 3);
  }
  if (tid < 64) xs[tid >> 5][T_ * 16 + (tid & 31)] = 0;
  for (int i = tid; i < V_ * G3; i += 1024) tabS[i] = table[i];
  for (int i = tid; i < 2 * 2 * 16 * SH; i += 1024) ((short*)hbuf)[i] = 0;
  if (tid < 2) gctr[tid] = 0;

  // ---- persistent A-fragments: W_hh tiles (pre-scaled), A[g=m][k=q*8+j] ----
  short8 wA[3][4];
#pragma unroll
  for (int s = 0; s < 3; ++s) {
    const float sc = (s < 2) ? -LOG2E : 2.f * LOG2E;
    const float* wrow = W_hh + (s * H_ + w * 16 + m) * H_;
#pragma unroll
    for (int ks = 0; ks < 4; ++ks) {
      const float* p = wrow + ks * 32 + q * 8;
      short8 f;
#pragma unroll
      for (int jj = 0; jj < 8; ++jj) f[jj] = bf16s(p[jj] * sc);
      wA[s][ks] = f;
    }
  }

  const int c0 = w * 16 + q * 4;    // this lane's h-col base
  float4v bhnC;                     // a2 chain C-init: b_hh_n * 2log2e
  {
    const float* p = b_hh + 2 * H_ + c0;
#pragma unroll
    for (int i = 0; i < 4; ++i) bhnC[i] = p[i] * 2.f * LOG2E;
  }
  float h_old[4] = {0.f, 0.f, 0.f, 0.f};

  __syncthreads();                  // one block-wide barrier: setup done

  // ---- per-group spin barrier (8 waves): release write -> count -> acquire ----
  int bt = 0;
  auto gbar = [&]() {
    bt += 8;
    if (lane == 0)
      __hip_atomic_fetch_add(&gctr[grp], 1, __ATOMIC_ACQ_REL,
                             __HIP_MEMORY_SCOPE_WORKGROUP);
    while (__hip_atomic_load(&gctr[grp], __ATOMIC_ACQUIRE,
                             __HIP_MEMORY_SCOPE_WORKGROUP) < bt) { }
  };

  // ---- prologue: gi(0) into set A; token byte of t=1 ----
  float4v gAR, gAZ, gAN, gBR, gBZ, gBN;
  int vb;
  {
    int v0 = xs[grp][m] & 3;
    const float* tb = &tabS[v0 * G3 + c0];
    gAR = *(const float4v*)(tb);
    gAZ = *(const float4v*)(tb + H_);
    gAN = *(const float4v*)(tb + 2 * H_);
    vb  = xs[grp][16 + m];
  }

  auto step = [&](int FROM, int TO, int t,
                  float4v& guR, float4v& guZ, float4v& guN,
                  float4v& glR, float4v& glZ, float4v& glN) {
    const short* rbp = &hbuf[grp][FROM][m * SH + q * 8];
    short8 h0 = *(const short8*)(rbp);
    short8 h1 = *(const short8*)(rbp + 32);
    short8 h2 = *(const short8*)(rbp + 64);
    short8 h3 = *(const short8*)(rbp + 96);

    // ---- all 12 MFMAs up front; a0 (r) leads, a2, a1 (z) last ----
    float4v a0 = MFMA16(wA[0][0], h0, guR);
    a0 = MFMA16(wA[0][1], h1, a0);
    a0 = MFMA16(wA[0][2], h2, a0);
    a0 = MFMA16(wA[0][3], h3, a0);
    float4v a2 = MFMA16(wA[2][0], h0, bhnC);
    a2 = MFMA16(wA[2][1], h1, a2);
    a2 = MFMA16(wA[2][2], h2, a2);
    a2 = MFMA16(wA[2][3], h3, a2);
    float4v a1 = MFMA16(wA[1][0], h0, guZ);
    a1 = MFMA16(wA[1][1], h1, a1);
    a1 = MFMA16(wA[1][2], h2, a1);
    a1 = MFMA16(wA[1][3], h3, a1);

    // ---- r = rcp(1+Er) under the queue drain ----
    float Er0 = __builtin_amdgcn_exp2f(a0[0]);
    float Er1 = __builtin_amdgcn_exp2f(a0[1]);
    float Er2 = __builtin_amdgcn_exp2f(a0[2]);
    float Er3 = __builtin_amdgcn_exp2f(a0[3]);
    float r0 = __builtin_amdgcn_rcpf(1.f + Er0);
    float r1 = __builtin_amdgcn_rcpf(1.f + Er1);
    float r2 = __builtin_amdgcn_rcpf(1.f + Er2);
    float r3 = __builtin_amdgcn_rcpf(1.f + Er3);

    // ---- next-step gi preloads into the other register set ----
    int vb2 = xs[grp][(t + 2) * 16 + m];
    const float* tbn = &tabS[(vb & 3) * G3 + c0];
    glR = *(const float4v*)(tbn);
    glZ = *(const float4v*)(tbn + H_);
    glN = *(const float4v*)(tbn + 2 * H_);
    vb = vb2;

    // ---- fused tail: h' = [e2n(Ez+h) + (h-Ez)] * rcp[(e2n+1)(1+Ez)] ----
    float np20 = __fmaf_rn(r0, a2[0], guN[0]);
    float np21 = __fmaf_rn(r1, a2[1], guN[1]);
    float np22 = __fmaf_rn(r2, a2[2], guN[2]);
    float np23 = __fmaf_rn(r3, a2[3], guN[3]);
    float e2n0 = __builtin_amdgcn_exp2f(np20);
    float e2n1 = __builtin_amdgcn_exp2f(np21);
    float e2n2 = __builtin_amdgcn_exp2f(np22);
    float e2n3 = __builtin_amdgcn_exp2f(np23);
    float Ez0 = __builtin_amdgcn_exp2f(a1[0]);
    float Ez1 = __builtin_amdgcn_exp2f(a1[1]);
    float Ez2 = __builtin_amdgcn_exp2f(a1[2]);
    float Ez3 = __builtin_amdgcn_exp2f(a1[3]);
    float num0 = __fmaf_rn(e2n0, Ez0 + h_old[0], h_old[0] - Ez0);
    float num1 = __fmaf_rn(e2n1, Ez1 + h_old[1], h_old[1] - Ez1);
    float num2 = __fmaf_rn(e2n2, Ez2 + h_old[2], h_old[2] - Ez2);
    float num3 = __fmaf_rn(e2n3, Ez3 + h_old[3], h_old[3] - Ez3);
    float den0 = (e2n0 + 1.f) * (1.f + Ez0);
    float den1 = (e2n1 + 1.f) * (1.f + Ez1);
    float den2 = (e2n2 + 1.f) * (1.f + Ez2);
    float den3 = (e2n3 + 1.f) * (1.f + Ez3);
    float hn0 = num0 * __builtin_amdgcn_rcpf(den0);
    float hn1 = num1 * __builtin_amdgcn_rcpf(den1);
    float hn2 = num2 * __builtin_amdgcn_rcpf(den2);
    float hn3 = num3 * __builtin_amdgcn_rcpf(den3);
    h_old[0] = hn0; h_old[1] = hn1; h_old[2] = hn2; h_old[3] = hn3;
    union { float ff; unsigned int u; } c0u, c1u, c2u, c3u;
    c0u.ff = hn0; c1u.ff = hn1; c2u.ff = hn2; c3u.ff = hn3;
    unsigned int pk0 = __builtin_amdgcn_perm(c1u.u + 0x8000u, c0u.u + 0x8000u, 0x07060302u);
    unsigned int pk1 = __builtin_amdgcn_perm(c3u.u + 0x8000u, c2u.u + 0x8000u, 0x07060302u);
    *(ull*)(&hbuf[grp][TO][m * SH + c0]) = ((ull)pk1 << 32) | pk0;
    gbar();                          // group-local barrier (NOT s_barrier)
  };

  for (int t = 0; t < T_; t += 2) {
    step(0, 1, t,     gAR, gAZ, gAN, gBR, gBZ, gBN);
    step(1, 0, t + 1, gBR, gBZ, gBN, gAR, gAZ, gAN);
  }

  // ---- epilogue: logits = hT @ W_fc^T + b_fc (per group) ----
#pragma unroll
  for (int i = 0; i < 4; ++i) hf[grp][m * H_ + c0 + i] = h_old[i];
  gbar();

  if (tid9 < 64) {
    int row = tid9 >> 2, vo = tid9 & 3;
    float s = b_fc[vo];
    const float* wv = W_fc + vo * H_;
    const float* hr = &hf[grp][row * H_];
#pragma unroll 4
    for (int k = 0; k < H_; k += 4)
      s += hr[k] * wv[k] + hr[k + 1] * wv[k + 1]
         + hr[k + 2] * wv[k + 2] + hr[k + 3] * wv[k + 3];
    out[(g0 + row) * V_ + vo] = s;
  }
}

extern "C" void kernel_launch(void* const* d_in, const int* in_sizes, int n_in,
                              void* d_out, int out_size, void* d_ws, size_t ws_size,
                              hipStream_t stream) {
  const int*   x    = (const int*)d_in[0];
  const float* emb  = (const float*)d_in[1];
  const float* W_ih = (const float*)d_in[2];
  const float* W_hh = (const float*)d_in[3];
  const float* b_ih = (const float*)d_in[4];
  const float* b_hh = (const float*)d_in[5];
  const float* W_fc = (const float*)d_in[6];
  const float* b_fc = (const float*)d_in[7];
  float* out   = (float*)d_out;
  float* table = (float*)d_ws;     // 4*384 fp32 = 6 KB

  gi_table_kernel<<<(V_ * G3 + 255) / 256, 256, 0, stream>>>(emb, W_ih, b_ih, b_hh, table);
  gru_kernel<<<B_ / 32, 1024, 0, stream>>>(x, W_hh, b_hh, W_fc, b_fc, table, out);
}

// Round 14
// 320.920 us; speedup vs baseline: 1.7381x; 1.7381x over previous
//
#include <hip/hip_runtime.h>
#include <hip/hip_bf16.h>

// GRU policy: B=2048, T=512, V=4, E=64, H=128.
// R13 = R9 (best: 295us kernel) + packed-fp32 (VOP3P v_pk_*) tail.
// Ledger: overlap-engineering 0-for-6 (R4 antiphase, R7 fences, R8 reorder,
// R10 setprio, R11 1-wave/SIMD, R12 spin-barrier groups) — step cost is the
// SUM of pipe occupancies: 466 MFMA + ~600 VALU/trans + LDS/latency ~ 1380cy.
// Only reducible term: VALU issue count. The ~32 scalar fp32 tail ops/lane
// pair into ~16 v_pk_fma/add/mul_f32; trans (exp2/rcp) stay scalar.
// Per wave/step: 12 MFMA, 7 ds_read_b128 + 1 ds_read_u8 + 1 ds_write_b64,
// 20 trans, ~46 VALU. 1 barrier/step. 128 blocks (structural: B/16 groups).

#define B_  2048
#define T_  512
#define V_  4
#define E_  64
#define H_  128
#define G3  384
#define SH  136            // h row stride (bf16 elems)

#define LOG2E 1.4426950408889634f

typedef __attribute__((ext_vector_type(8))) short  short8;   // 8 bf16
typedef __attribute__((ext_vector_type(4))) float  float4v;
typedef __attribute__((ext_vector_type(2))) float  f32x2;    // -> v_pk_* f32
typedef unsigned long long ull;

__device__ __forceinline__ short bf16s(float f) {            // RNE scalar (setup only)
  union { float ff; unsigned int u; } c; c.ff = f;
  return (short)((c.u + 0x7fffu + ((c.u >> 16) & 1u)) >> 16);
}

// table[v][g] = scale_g * (b_ih[g] + sum_e W_ih[g,e]*emb[v,e] (+ b_hh[g] for g<2H))
// scale_g = -log2e for r,z rows; +2*log2e for n rows (b_hh_n NOT folded).
__global__ void gi_table_kernel(const float* __restrict__ emb,
                                const float* __restrict__ W_ih,
                                const float* __restrict__ b_ih,
                                const float* __restrict__ b_hh,
                                float* __restrict__ table) {
  int gid = blockIdx.x * blockDim.x + threadIdx.x;
  if (gid >= V_ * G3) return;
  int v = gid / G3;
  int g = gid - v * G3;
  float acc = b_ih[g];
  if (g < 2 * H_) acc += b_hh[g];
  const float* wr = W_ih + g * E_;
  const float* er = emb + v * E_;
#pragma unroll 8
  for (int e = 0; e < E_; ++e) acc += wr[e] * er[e];
  table[gid] = acc * ((g < 2 * H_) ? -LOG2E : 2.f * LOG2E);
}

#define MFMA16(A, B, C) __builtin_amdgcn_mfma_f32_16x16x32_bf16((A), (B), (C), 0, 0, 0)

__global__ __launch_bounds__(512) void gru_kernel(
    const int* __restrict__ x, const float* __restrict__ W_hh,
    const float* __restrict__ b_hh, const float* __restrict__ W_fc,
    const float* __restrict__ b_fc, const float* __restrict__ table,
    float* __restrict__ out) {
  __shared__ __align__(16) short hbuf[2][16 * SH];          // bf16 h, double-buffered
  __shared__ __align__(16) unsigned char xs[(T_ + 2) * 16]; // tokens [t][row], 2 pad rows
  __shared__ __align__(16) float tabS[V_ * G3];             // gi table (pre-scaled)
  __shared__ __align__(16) float hf[16 * H_];               // epilogue fp32 h

  const int tid  = threadIdx.x;
  const int w    = tid >> 6;        // wave 0..7
  const int lane = tid & 63;
  const int m    = lane & 15;       // batch row (B/C col) and A gate-row
  const int q    = lane >> 4;       // quad
  const int g0   = blockIdx.x * 16;

  // ---- stage x -> xs[t][r] bytes; zero the 2 pad rows ----
  for (int i = tid; i < 16 * T_; i += 512) {
    int r = i >> 9;                 // 0..15
    int t = i & (T_ - 1);
    xs[t * 16 + r] = (unsigned char)(x[(g0 + r) * T_ + t] & 3);
  }
  if (tid < 32) xs[T_ * 16 + tid] = 0;
  // ---- stage gi table to LDS ----
  for (int i = tid; i < V_ * G3; i += 512) tabS[i] = table[i];
  // ---- h0 = 0 ----
  for (int i = tid; i < 16 * SH; i += 512) hbuf[0][i] = 0;

  // ---- persistent A-fragments: W_hh tiles (pre-scaled), A[g=m][k=q*8+j] ----
  short8 wA[3][4];
#pragma unroll
  for (int s = 0; s < 3; ++s) {
    const float sc = (s < 2) ? -LOG2E : 2.f * LOG2E;
    const float* wrow = W_hh + (s * H_ + w * 16 + m) * H_;
#pragma unroll
    for (int ks = 0; ks < 4; ++ks) {
      const float* p = wrow + ks * 32 + q * 8;
      short8 f;
#pragma unroll
      for (int jj = 0; jj < 8; ++jj) f[jj] = bf16s(p[jj] * sc);
      wA[s][ks] = f;
    }
  }

  const int c0 = w * 16 + q * 4;    // this lane's h-col base
  float4v bhnC;                     // a2 chain C-init: b_hh_n * 2log2e
  {
    const float* p = b_hh + 2 * H_ + c0;
#pragma unroll
    for (int i = 0; i < 4; ++i) bhnC[i] = p[i] * 2.f * LOG2E;
  }
  f32x2 hA = {0.f, 0.f}, hB = {0.f, 0.f};   // h for rows (0,1) and (2,3) packed

  __syncthreads();

  // ---- prologue: gi(0) into set A; token byte of t=1 ----
  float4v gAR, gAZ, gAN, gBR, gBZ, gBN;
  int vb;
  {
    int v0 = xs[m] & 3;
    const float* tb = &tabS[v0 * G3 + c0];
    gAR = *(const float4v*)(tb);
    gAZ = *(const float4v*)(tb + H_);
    gAN = *(const float4v*)(tb + 2 * H_);
    vb  = xs[16 + m];
  }

  const f32x2 one2 = {1.f, 1.f};

  auto step = [&](int FROM, int TO, int t,
                  float4v& guR, float4v& guZ, float4v& guN,     // gi used this step
                  float4v& glR, float4v& glZ, float4v& glN) {   // gi loaded for next
    // h fragments — the ONLY LDS reads that gate this step's MFMAs
    const short* rbp = &hbuf[FROM][m * SH + q * 8];
    short8 h0 = *(const short8*)(rbp);
    short8 h1 = *(const short8*)(rbp + 32);
    short8 h2 = *(const short8*)(rbp + 64);
    short8 h3 = *(const short8*)(rbp + 96);

    // ---- all 12 MFMAs up front; a0 (r) leads, a2, a1 (z) last ----
    float4v a0 = MFMA16(wA[0][0], h0, guR);
    a0 = MFMA16(wA[0][1], h1, a0);
    a0 = MFMA16(wA[0][2], h2, a0);
    a0 = MFMA16(wA[0][3], h3, a0);
    float4v a2 = MFMA16(wA[2][0], h0, bhnC);
    a2 = MFMA16(wA[2][1], h1, a2);
    a2 = MFMA16(wA[2][2], h2, a2);
    a2 = MFMA16(wA[2][3], h3, a2);
    float4v a1 = MFMA16(wA[1][0], h0, guZ);
    a1 = MFMA16(wA[1][1], h1, a1);
    a1 = MFMA16(wA[1][2], h2, a1);
    a1 = MFMA16(wA[1][3], h3, a1);

    // ---- r = rcp(1+Er): scalar trans, under the queue drain ----
    float r0 = __builtin_amdgcn_rcpf(1.f + __builtin_amdgcn_exp2f(a0[0]));
    float r1 = __builtin_amdgcn_rcpf(1.f + __builtin_amdgcn_exp2f(a0[1]));
    float r2 = __builtin_amdgcn_rcpf(1.f + __builtin_amdgcn_exp2f(a0[2]));
    float r3 = __builtin_amdgcn_rcpf(1.f + __builtin_amdgcn_exp2f(a0[3]));

    // ---- next-step gi preloads into the other register set ----
    int vb2 = xs[(t + 2) * 16 + m];
    const float* tbn = &tabS[(vb & 3) * G3 + c0];
    glR = *(const float4v*)(tbn);
    glZ = *(const float4v*)(tbn + H_);
    glN = *(const float4v*)(tbn + 2 * H_);
    vb = vb2;

    // ---- packed fused tail: h' = [e2n(Ez+h)+(h-Ez)] * rcp[(e2n+1)(1+Ez)] ----
    f32x2 rA = {r0, r1},           rB = {r2, r3};
    f32x2 a2A = {a2[0], a2[1]},    a2B = {a2[2], a2[3]};
    f32x2 gnA = {guN[0], guN[1]},  gnB = {guN[2], guN[3]};
    f32x2 npA = rA * a2A + gnA;                    // v_pk_fma_f32
    f32x2 npB = rB * a2B + gnB;
    f32x2 eA = {__builtin_amdgcn_exp2f(npA.x), __builtin_amdgcn_exp2f(npA.y)};
    f32x2 eB = {__builtin_amdgcn_exp2f(npB.x), __builtin_amdgcn_exp2f(npB.y)};
    f32x2 EzA = {__builtin_amdgcn_exp2f(a1[0]), __builtin_amdgcn_exp2f(a1[1])};
    f32x2 EzB = {__builtin_amdgcn_exp2f(a1[2]), __builtin_amdgcn_exp2f(a1[3])};
    f32x2 numA = eA * (EzA + hA) + (hA - EzA);     // pk_add, pk_fma, pk_add(neg)
    f32x2 numB = eB * (EzB + hB) + (hB - EzB);
    f32x2 denA = (eA + one2) * (one2 + EzA);       // pk_add x2, pk_mul
    f32x2 denB = (eB + one2) * (one2 + EzB);
    f32x2 rcA = {__builtin_amdgcn_rcpf(denA.x), __builtin_amdgcn_rcpf(denA.y)};
    f32x2 rcB = {__builtin_amdgcn_rcpf(denB.x), __builtin_amdgcn_rcpf(denB.y)};
    hA = numA * rcA;                               // pk_mul
    hB = numB * rcB;
    union { float ff; unsigned int u; } c0u, c1u, c2u, c3u;
    c0u.ff = hA.x; c1u.ff = hA.y; c2u.ff = hB.x; c3u.ff = hB.y;
    unsigned int pk0 = __builtin_amdgcn_perm(c1u.u + 0x8000u, c0u.u + 0x8000u, 0x07060302u);
    unsigned int pk1 = __builtin_amdgcn_perm(c3u.u + 0x8000u, c2u.u + 0x8000u, 0x07060302u);
    *(ull*)(&hbuf[TO][m * SH + c0]) = ((ull)pk1 << 32) | pk0;
    __syncthreads();
  };

  for (int t = 0; t < T_; t += 2) {
    step(0, 1, t,     gAR, gAZ, gAN, gBR, gBZ, gBN);
    step(1, 0, t + 1, gBR, gBZ, gBN, gAR, gAZ, gAN);
  }

  // ---- epilogue: logits = hT @ W_fc^T + b_fc ----
  hf[m * H_ + c0 + 0] = hA.x;
  hf[m * H_ + c0 + 1] = hA.y;
  hf[m * H_ + c0 + 2] = hB.x;
  hf[m * H_ + c0 + 3] = hB.y;
  __syncthreads();

  if (tid < 64) {
    int row = tid >> 2, vo = tid & 3;
    float s = b_fc[vo];
    const float* wv = W_fc + vo * H_;
    const float* hr = &hf[row * H_];
#pragma unroll 4
    for (int k = 0; k < H_; k += 4)
      s += hr[k] * wv[k] + hr[k + 1] * wv[k + 1]
         + hr[k + 2] * wv[k + 2] + hr[k + 3] * wv[k + 3];
    out[(g0 + row) * V_ + vo] = s;
  }
}

extern "C" void kernel_launch(void* const* d_in, const int* in_sizes, int n_in,
                              void* d_out, int out_size, void* d_ws, size_t ws_size,
                              hipStream_t stream) {
  const int*   x    = (const int*)d_in[0];
  const float* emb  = (const float*)d_in[1];
  const float* W_ih = (const float*)d_in[2];
  const float* W_hh = (const float*)d_in[3];
  const float* b_ih = (const float*)d_in[4];
  const float* b_hh = (const float*)d_in[5];
  const float* W_fc = (const float*)d_in[6];
  const float* b_fc = (const float*)d_in[7];
  float* out   = (float*)d_out;
  float* table = (float*)d_ws;     // 4*384 fp32 = 6 KB

  gi_table_kernel<<<(V_ * G3 + 255) / 256, 256, 0, stream>>>(emb, W_ih, b_ih, b_hh, table);
  gru_kernel<<<B_ / 16, 512, 0, stream>>>(x, W_hh, b_hh, W_fc, b_fc, table, out);
}